// Round 5
// baseline (176.590 us; speedup 1.0000x reference)
//
#include <hip/hip_runtime.h>
#include <stdint.h>

// Problem constants (fixed by the reference)
#define NV    8192   // variables
#define NC    4096   // checks
#define DC    6      // edges per check
#define DV    3      // edges per variable
#define NE    24576  // edges
#define NITER 5
#define BATCH 2048

// ---------------------------------------------------------------------------
// Setup 1: per-var edge lists (sorted ascending so the np.add.at association
// and slot ranks are deterministic).
// ---------------------------------------------------------------------------

__global__ void build_v2e(const int* __restrict__ cols, int* __restrict__ cnt,
                          unsigned short* __restrict__ v2e_tmp) {
  int e = blockIdx.x * blockDim.x + threadIdx.x;
  if (e >= NE) return;
  int v = cols[e];
  int s = atomicAdd(&cnt[v], 1);
  v2e_tmp[v * DV + s] = (unsigned short)e;
}

// Setup 2: per-edge slot codes, contiguous per check: cslot[e] = k*NV + v,
// where k = rank of edge e among its var's ascending edges. (e = c*6 + j.)
__global__ void invert_slots(const unsigned short* __restrict__ v2e_tmp,
                             unsigned short* __restrict__ cslot) {
  int v = blockIdx.x * blockDim.x + threadIdx.x;
  if (v >= NV) return;
  int a = v2e_tmp[v * 3 + 0];
  int b = v2e_tmp[v * 3 + 1];
  int c = v2e_tmp[v * 3 + 2];
  int t;
  if (a > b) { t = a; a = b; b = t; }
  if (b > c) { t = b; b = c; c = t; }
  if (a > b) { t = a; a = b; b = t; }
  cslot[a] = (unsigned short)(0 * NV + v);
  cslot[b] = (unsigned short)(1 * NV + v);
  cslot[c] = (unsigned short)(2 * NV + v);
}

// ---------------------------------------------------------------------------
// Setup 3: bank-aware edge schedule, one wave per group of 64 consecutive
// checks (exactly the checks one decode wave touches per r in lockstep).
// Stage 1: first-fit auction with per-lane rotated candidate order, <=2 lanes
//          per bank per row (2-way is free on CDNA4 LDS, m136).
// Stage 2: 4 passes of lane-local row-pair swap improvement against live
//          per-row bank histograms, cost(n) = ceil(n/2)-1.
// Any per-check edge permutation is BIT-EXACT for the decoder (check update
// is order-symmetric), so scheduler races never affect d_out.
// ---------------------------------------------------------------------------

__device__ __forceinline__ int icost(int n) {
  return (n > 2) ? (((n + 1) >> 1) - 1) : 0;
}

__global__ __launch_bounds__(64) void greedy_schedule(
    const unsigned short* __restrict__ cslot, unsigned int* __restrict__ slotp) {
  __shared__ unsigned short sl[64][6];
  __shared__ unsigned char perm[64][6];
  __shared__ int cnt[6][32];

  const int l = threadIdx.x;
  const int c = blockIdx.x * 64 + l;

  const unsigned int* cs32 = (const unsigned int*)cslot;
  unsigned int a0 = cs32[c * 3 + 0];
  unsigned int a1 = cs32[c * 3 + 1];
  unsigned int a2 = cs32[c * 3 + 2];
  sl[l][0] = (unsigned short)(a0 & 0xffffu); sl[l][1] = (unsigned short)(a0 >> 16);
  sl[l][2] = (unsigned short)(a1 & 0xffffu); sl[l][3] = (unsigned short)(a1 >> 16);
  sl[l][4] = (unsigned short)(a2 & 0xffffu); sl[l][5] = (unsigned short)(a2 >> 16);

  for (int t = l; t < 192; t += 64) ((int*)cnt)[t] = 0;
  __syncthreads();

  // ---- Stage 1: rotated first-fit, <=2 per bank per row -------------------
  unsigned int used = 0;
  for (int j = 0; j < 6; ++j) {
    int placed = -1;
    for (int kk = 0; kk < 6; ++kk) {
      int k = (kk + l + j) % 6;          // decorrelate lanes
      if (used & (1u << k)) continue;
      int bk = sl[l][k] & 31;
      int old = atomicAdd(&cnt[j][bk], 1);
      if (old < 2) { placed = k; break; }
      atomicSub(&cnt[j][bk], 1);
    }
    if (placed < 0) {                    // forced: count it so stage 2 sees it
      for (int k = 0; k < 6; ++k)
        if (!(used & (1u << k))) { placed = k; break; }
      atomicAdd(&cnt[j][sl[l][placed] & 31], 1);
    }
    used |= (1u << placed);
    perm[l][j] = (unsigned char)placed;
    __syncthreads();
  }

  // ---- Stage 2: lane-local swap improvement -------------------------------
  for (int pass = 0; pass < 4; ++pass) {
    for (int j1 = 0; j1 < 6; ++j1) {
      for (int j2 = j1 + 1; j2 < 6; ++j2) {
        int k1 = perm[l][j1], k2 = perm[l][j2];
        int b1 = sl[l][k1] & 31, b2 = sl[l][k2] & 31;
        if (b1 != b2) {
          int c11 = cnt[j1][b1], c12 = cnt[j1][b2];
          int c21 = cnt[j2][b1], c22 = cnt[j2][b2];
          int dOld = icost(c11) + icost(c12) + icost(c21) + icost(c22);
          int dNew = icost(c11 - 1) + icost(c12 + 1) + icost(c22 - 1) + icost(c21 + 1);
          if (dNew < dOld) {
            atomicSub(&cnt[j1][b1], 1); atomicAdd(&cnt[j1][b2], 1);
            atomicSub(&cnt[j2][b2], 1); atomicAdd(&cnt[j2][b1], 1);
            perm[l][j1] = (unsigned char)k2; perm[l][j2] = (unsigned char)k1;
          }
        }
        __syncthreads();
      }
    }
  }

  unsigned short pm[6];
#pragma unroll
  for (int j = 0; j < 6; ++j) pm[j] = sl[l][perm[l][j]];
  slotp[0 * NC + c] = (unsigned int)pm[0] | ((unsigned int)pm[1] << 16);
  slotp[1 * NC + c] = (unsigned int)pm[2] | ((unsigned int)pm[3] << 16);
  slotp[2 * NC + c] = (unsigned int)pm[4] | ((unsigned int)pm[5] << 16);
}

// ---------------------------------------------------------------------------
// Fused decoder: one workgroup per batch element; 96 KB var-major slot array.
// Phase A (float2-vectorized, contiguous): slots c2v -> v2c = vl - c2v.
// Phase B (random, bank-scheduled rows, reg-preloaded addrs): v2c -> c2v.
// ---------------------------------------------------------------------------

__global__ __launch_bounds__(1024) void decode_kernel(
    const float* __restrict__ ch, const float* __restrict__ wts,
    const unsigned int* __restrict__ slotp, float* __restrict__ out) {
  __shared__ float s_msg[NE];   // 96 KB

  const int tid = threadIdx.x;
  const int b = blockIdx.x;
  const float2* ch2 = (const float2*)(ch + (size_t)b * NV);

  float2 chreg[4];
#pragma unroll
  for (int p = 0; p < 4; ++p) chreg[p] = ch2[tid + p * 1024];

  float w[NITER];
#pragma unroll
  for (int i = 0; i < NITER; ++i) w[i] = wts[i];

  // Preload the 6 (scheduled) slot indices for each of this thread's 4 checks.
  int idx[4][6];
#pragma unroll
  for (int r = 0; r < 4; ++r) {
    int c = tid + r * 1024;
    unsigned int p0 = slotp[c];
    unsigned int p1 = slotp[NC + c];
    unsigned int p2 = slotp[2 * NC + c];
    idx[r][0] = (int)(p0 & 0xFFFFu); idx[r][1] = (int)(p0 >> 16);
    idx[r][2] = (int)(p1 & 0xFFFFu); idx[r][3] = (int)(p1 >> 16);
    idx[r][4] = (int)(p2 & 0xFFFFu); idx[r][5] = (int)(p2 >> 16);
  }

  float2* m0 = (float2*)&s_msg[0];
  float2* m1 = (float2*)&s_msg[NV];
  float2* m2 = (float2*)&s_msg[2 * NV];

  // ---- it=0 Phase A: c2v==0 -> v2c = ch in all 3 planes -------------------
#pragma unroll
  for (int p = 0; p < 4; ++p) {
    int i2 = p * 1024 + tid;
    float2 v = chreg[p];
    m0[i2] = v; m1[i2] = v; m2[i2] = v;
  }
  __syncthreads();

  for (int it = 0; it < NITER; ++it) {
    const float wi = w[it];

    // ---- Phase B: check update; slots v2c -> c2v --------------------------
#pragma unroll
    for (int r = 0; r < 4; ++r) {
      unsigned int u[6];
      float m1v = INFINITY, m2v = INFINITY;
      unsigned int xs = 0u;
#pragma unroll
      for (int j = 0; j < 6; ++j) {
        float t = s_msg[idx[r][j]];
        unsigned int uu = __float_as_uint(t);
        u[j] = uu;
        xs ^= uu;
        float a = fabsf(t);
        m2v = fminf(m2v, fmaxf(m1v, a));   // uses OLD m1v: exact 2nd-min
        m1v = fminf(m1v, a);
      }
      const bool anyz = (m1v == 0.0f);
      const float m1w = m1v * wi;
      const float m2w = m2v * wi;
#pragma unroll
      for (int j = 0; j < 6; ++j) {
        float a = __uint_as_float(u[j] & 0x7FFFFFFFu);
        float mag = (a == m1v) ? m2w : m1w;  // ties: m2v==m1v, matches ref
        unsigned int s = (xs ^ u[j]) & 0x80000000u;
        float o = __uint_as_float(__float_as_uint(mag) ^ s);
        if (anyz) o = 0.0f;
        s_msg[idx[r][j]] = o;
      }
    }
    __syncthreads();

    // ---- Phase A: variable update; slots c2v -> v2c (float2) --------------
    if (it < NITER - 1) {
#pragma unroll
      for (int p = 0; p < 4; ++p) {
        int i2 = p * 1024 + tid;
        float2 c0 = m0[i2], c1 = m1[i2], c2 = m2[i2];
        float2 cr = chreg[p];
        float2 vl;
        vl.x = cr.x + ((c0.x + c1.x) + c2.x);   // np.add.at association
        vl.y = cr.y + ((c0.y + c1.y) + c2.y);
        float2 o0 = {vl.x - c0.x, vl.y - c0.y};
        float2 o1 = {vl.x - c1.x, vl.y - c1.y};
        float2 o2 = {vl.x - c2.x, vl.y - c2.y};
        m0[i2] = o0; m1[i2] = o1; m2[i2] = o2;
      }
      __syncthreads();
    }
  }

  // ---- Final: out = ch + ((c0+c1)+c2), float2 stores ----------------------
  float2* orow2 = (float2*)(out + (size_t)b * NV);
#pragma unroll
  for (int p = 0; p < 4; ++p) {
    int i2 = p * 1024 + tid;
    float2 c0 = m0[i2], c1 = m1[i2], c2 = m2[i2];
    float2 cr = chreg[p];
    float2 o;
    o.x = cr.x + ((c0.x + c1.x) + c2.x);
    o.y = cr.y + ((c0.y + c1.y) + c2.y);
    orow2[i2] = o;
  }
}

// ---------------------------------------------------------------------------

extern "C" void kernel_launch(void* const* d_in, const int* in_sizes, int n_in,
                              void* d_out, int out_size, void* d_ws, size_t ws_size,
                              hipStream_t stream) {
  (void)in_sizes; (void)n_in; (void)out_size; (void)ws_size;

  const float* ch   = (const float*)d_in[0];   // [BATCH, NV] f32
  const float* wts  = (const float*)d_in[1];   // [NITER, 1] f32
  const int*  Hcols = (const int*)d_in[3];     // [NE] i32
  float* out = (float*)d_out;

  char* ws = (char*)d_ws;
  int*            cnt     = (int*)(ws + 0);                  // 32768 B
  unsigned short* v2e_tmp = (unsigned short*)(ws + 32768);   // 49152 B
  unsigned short* cslot   = (unsigned short*)(ws + 81920);   // 49152 B
  unsigned int*   slotp   = (unsigned int*)(ws + 131072);    // 49152 B
  // total ws use: 180224 B

  hipMemsetAsync(cnt, 0, NV * sizeof(int), stream);
  build_v2e<<<(NE + 255) / 256, 256, 0, stream>>>(Hcols, cnt, v2e_tmp);
  invert_slots<<<(NV + 255) / 256, 256, 0, stream>>>(v2e_tmp, cslot);
  greedy_schedule<<<NC / 64, 64, 0, stream>>>(cslot, slotp);

  decode_kernel<<<BATCH, 1024, 0, stream>>>(ch, wts, slotp, out);
}

// Round 6
// 162.378 us; speedup vs baseline: 1.0875x; 1.0875x over previous
//
#include <hip/hip_runtime.h>
#include <stdint.h>

// Problem constants (fixed by the reference)
#define NV    8192   // variables
#define NC    4096   // checks
#define DC    6      // edges per check
#define DV    3      // edges per variable
#define NE    24576  // edges
#define NITER 5
#define BATCH 2048

// ---------------------------------------------------------------------------
// Setup 1: per-var edge lists (sorted ascending so the np.add.at association
// and slot ranks are deterministic).
// ---------------------------------------------------------------------------

__global__ void build_v2e(const int* __restrict__ cols, int* __restrict__ cnt,
                          unsigned short* __restrict__ v2e_tmp) {
  int e = blockIdx.x * blockDim.x + threadIdx.x;
  if (e >= NE) return;
  int v = cols[e];
  int s = atomicAdd(&cnt[v], 1);
  v2e_tmp[v * DV + s] = (unsigned short)e;
}

// Setup 2: per-edge slot codes, contiguous per check: cslot[e] = k*NV + v,
// where k = rank of edge e among its var's ascending edges. (e = c*6 + j.)
__global__ void invert_slots(const unsigned short* __restrict__ v2e_tmp,
                             unsigned short* __restrict__ cslot) {
  int v = blockIdx.x * blockDim.x + threadIdx.x;
  if (v >= NV) return;
  int a = v2e_tmp[v * 3 + 0];
  int b = v2e_tmp[v * 3 + 1];
  int c = v2e_tmp[v * 3 + 2];
  int t;
  if (a > b) { t = a; a = b; b = t; }
  if (b > c) { t = b; b = c; c = t; }
  if (a > b) { t = a; a = b; b = t; }
  cslot[a] = (unsigned short)(0 * NV + v);
  cslot[b] = (unsigned short)(1 * NV + v);
  cslot[c] = (unsigned short)(2 * NV + v);
}

// ---------------------------------------------------------------------------
// Setup 3: QUARTER-granular bank schedule. LDS model (from stride µbench):
// a wave64 b32 op is serviced one 16-lane quarter per beat; lanes of the SAME
// quarter hitting the same bank serialize. So the objective is, per row j and
// per quarter q, at most 1 lane per bank (slot & 31; note bank = var & 31
// since NV is a multiple of 32).
// Stage 1: strict auction (claim a FREE bank in your quarter, rotated scan),
//          relaxed fallback (min-count unused candidate).
// Stage 2: 4 parity-staggered passes of row-pair swap improvement with
//          quarter cost (n-1)+.
// Any per-check edge permutation is BIT-EXACT for the decoder (check update
// is order-symmetric), so scheduler races never affect d_out.
// ---------------------------------------------------------------------------

__device__ __forceinline__ int qc(int n) { return (n > 1) ? (n - 1) : 0; }

__global__ __launch_bounds__(64) void greedy_schedule(
    const unsigned short* __restrict__ cslot, unsigned int* __restrict__ slotp) {
  __shared__ unsigned short sl[64][6];
  __shared__ unsigned char perm[64][6];
  __shared__ int cnt[6][4][32];   // row, quarter, bank

  const int l = threadIdx.x;
  const int q = l >> 4;
  const int c = blockIdx.x * 64 + l;

  const unsigned int* cs32 = (const unsigned int*)cslot;
  unsigned int a0 = cs32[c * 3 + 0];
  unsigned int a1 = cs32[c * 3 + 1];
  unsigned int a2 = cs32[c * 3 + 2];
  sl[l][0] = (unsigned short)(a0 & 0xffffu); sl[l][1] = (unsigned short)(a0 >> 16);
  sl[l][2] = (unsigned short)(a1 & 0xffffu); sl[l][3] = (unsigned short)(a1 >> 16);
  sl[l][4] = (unsigned short)(a2 & 0xffffu); sl[l][5] = (unsigned short)(a2 >> 16);

  for (int t = l; t < 6 * 4 * 32; t += 64) ((int*)cnt)[t] = 0;
  __syncthreads();

  // ---- Stage 1: strict (free-bank-in-quarter) auction, relaxed fallback ---
  unsigned int used = 0;
  for (int j = 0; j < 6; ++j) {
    int placed = -1;
    for (int kk = 0; kk < 6; ++kk) {
      int k = (kk + l) % 6;              // decorrelate lane scan order
      if (used & (1u << k)) continue;
      int bk = sl[l][k] & 31;
      if (atomicAdd(&cnt[j][q][bk], 1) == 0) { placed = k; break; }
      atomicSub(&cnt[j][q][bk], 1);
    }
    if (placed < 0) {                    // relaxed: min-count unused candidate
      int bc = 1 << 30;
      for (int k = 0; k < 6; ++k) {
        if (used & (1u << k)) continue;
        int cc = cnt[j][q][sl[l][k] & 31];
        if (cc < bc) { bc = cc; placed = k; }
      }
      atomicAdd(&cnt[j][q][sl[l][placed] & 31], 1);
    }
    used |= (1u << placed);
    perm[l][j] = (unsigned char)placed;
    __syncthreads();
  }

  // ---- Stage 2: quarter-cost swap improvement, parity-staggered -----------
  for (int pass = 0; pass < 4; ++pass) {
    for (int s = 0; s < 2; ++s) {
      for (int j1 = 0; j1 < 6; ++j1) {
        for (int j2 = j1 + 1; j2 < 6; ++j2) {
          if ((l & 1) == s) {
            int k1 = perm[l][j1], k2 = perm[l][j2];
            int b1 = sl[l][k1] & 31, b2 = sl[l][k2] & 31;
            if (b1 != b2) {
              int c11 = cnt[j1][q][b1], c12 = cnt[j1][q][b2];
              int c21 = cnt[j2][q][b1], c22 = cnt[j2][q][b2];
              int dOld = qc(c11) + qc(c12) + qc(c21) + qc(c22);
              int dNew = qc(c11 - 1) + qc(c12 + 1) + qc(c21 + 1) + qc(c22 - 1);
              if (dNew < dOld) {
                atomicSub(&cnt[j1][q][b1], 1); atomicAdd(&cnt[j1][q][b2], 1);
                atomicSub(&cnt[j2][q][b2], 1); atomicAdd(&cnt[j2][q][b1], 1);
                perm[l][j1] = (unsigned char)k2; perm[l][j2] = (unsigned char)k1;
              }
            }
          }
          __syncthreads();
        }
      }
    }
  }

  unsigned short pm[6];
#pragma unroll
  for (int j = 0; j < 6; ++j) pm[j] = sl[l][perm[l][j]];
  slotp[0 * NC + c] = (unsigned int)pm[0] | ((unsigned int)pm[1] << 16);
  slotp[1 * NC + c] = (unsigned int)pm[2] | ((unsigned int)pm[3] << 16);
  slotp[2 * NC + c] = (unsigned int)pm[4] | ((unsigned int)pm[5] << 16);
}

// ---------------------------------------------------------------------------
// Fused decoder (R4-verbatim): one workgroup per batch element; 96 KB
// var-major slot array. Phase A (float4, contiguous): c2v -> v2c = vl - c2v.
// Phase B (random, bank-scheduled rows, reg-preloaded addrs): v2c -> c2v.
// ---------------------------------------------------------------------------

__global__ __launch_bounds__(1024) void decode_kernel(
    const float* __restrict__ ch, const float* __restrict__ wts,
    const unsigned int* __restrict__ slotp, float* __restrict__ out) {
  __shared__ float s_msg[NE];   // 96 KB

  const int tid = threadIdx.x;
  const int b = blockIdx.x;
  const float* chrow = ch + (size_t)b * NV;
  const float4* ch4 = (const float4*)chrow;

  float4 chreg[2];
  chreg[0] = ch4[tid];           // vars 4*tid .. 4*tid+3
  chreg[1] = ch4[1024 + tid];    // vars 4096+4*tid ..

  float w[NITER];
#pragma unroll
  for (int i = 0; i < NITER; ++i) w[i] = wts[i];

  // Preload the 6 (scheduled) slot indices for each of this thread's 4 checks.
  int idx[4][6];
#pragma unroll
  for (int r = 0; r < 4; ++r) {
    int c = tid + r * 1024;
    unsigned int p0 = slotp[c];
    unsigned int p1 = slotp[NC + c];
    unsigned int p2 = slotp[2 * NC + c];
    idx[r][0] = (int)(p0 & 0xFFFFu); idx[r][1] = (int)(p0 >> 16);
    idx[r][2] = (int)(p1 & 0xFFFFu); idx[r][3] = (int)(p1 >> 16);
    idx[r][4] = (int)(p2 & 0xFFFFu); idx[r][5] = (int)(p2 >> 16);
  }

  float4* m0 = (float4*)&s_msg[0];
  float4* m1 = (float4*)&s_msg[NV];
  float4* m2 = (float4*)&s_msg[2 * NV];

  // ---- it=0 Phase A: c2v==0 -> v2c = ch in all 3 planes -------------------
#pragma unroll
  for (int p = 0; p < 2; ++p) {
    int i4 = p * 1024 + tid;
    float4 v = chreg[p];
    m0[i4] = v; m1[i4] = v; m2[i4] = v;
  }
  __syncthreads();

  for (int it = 0; it < NITER; ++it) {
    const float wi = w[it];

    // ---- Phase B: check update; slots v2c -> c2v --------------------------
#pragma unroll
    for (int r = 0; r < 4; ++r) {
      unsigned int u[6];
      float m1v = INFINITY, m2v = INFINITY;
      unsigned int xs = 0u;
#pragma unroll
      for (int j = 0; j < 6; ++j) {
        float t = s_msg[idx[r][j]];
        unsigned int uu = __float_as_uint(t);
        u[j] = uu;
        xs ^= uu;
        float a = fabsf(t);
        m2v = fminf(m2v, fmaxf(m1v, a));   // uses OLD m1v: exact 2nd-min
        m1v = fminf(m1v, a);
      }
      const bool anyz = (m1v == 0.0f);
      const float m1w = m1v * wi;
      const float m2w = m2v * wi;
#pragma unroll
      for (int j = 0; j < 6; ++j) {
        float a = __uint_as_float(u[j] & 0x7FFFFFFFu);
        float mag = (a == m1v) ? m2w : m1w;  // ties: m2v==m1v, matches ref
        unsigned int s = (xs ^ u[j]) & 0x80000000u;
        float o = __uint_as_float(__float_as_uint(mag) ^ s);
        if (anyz) o = 0.0f;
        s_msg[idx[r][j]] = o;
      }
    }
    __syncthreads();

    // ---- Phase A: variable update; slots c2v -> v2c (float4) --------------
    if (it < NITER - 1) {
#pragma unroll
      for (int p = 0; p < 2; ++p) {
        int i4 = p * 1024 + tid;
        float4 c0 = m0[i4], c1 = m1[i4], c2 = m2[i4];
        float4 cr = chreg[p];
        float4 vl;
        vl.x = cr.x + ((c0.x + c1.x) + c2.x);   // np.add.at association
        vl.y = cr.y + ((c0.y + c1.y) + c2.y);
        vl.z = cr.z + ((c0.z + c1.z) + c2.z);
        vl.w = cr.w + ((c0.w + c1.w) + c2.w);
        float4 o0 = {vl.x - c0.x, vl.y - c0.y, vl.z - c0.z, vl.w - c0.w};
        float4 o1 = {vl.x - c1.x, vl.y - c1.y, vl.z - c1.z, vl.w - c1.w};
        float4 o2 = {vl.x - c2.x, vl.y - c2.y, vl.z - c2.z, vl.w - c2.w};
        m0[i4] = o0; m1[i4] = o1; m2[i4] = o2;
      }
      __syncthreads();
    }
  }

  // ---- Final: out = ch + ((c0+c1)+c2), float4 stores ----------------------
  float4* orow4 = (float4*)(out + (size_t)b * NV);
#pragma unroll
  for (int p = 0; p < 2; ++p) {
    int i4 = p * 1024 + tid;
    float4 c0 = m0[i4], c1 = m1[i4], c2 = m2[i4];
    float4 cr = chreg[p];
    float4 o;
    o.x = cr.x + ((c0.x + c1.x) + c2.x);
    o.y = cr.y + ((c0.y + c1.y) + c2.y);
    o.z = cr.z + ((c0.z + c1.z) + c2.z);
    o.w = cr.w + ((c0.w + c1.w) + c2.w);
    orow4[i4] = o;
  }
}

// ---------------------------------------------------------------------------

extern "C" void kernel_launch(void* const* d_in, const int* in_sizes, int n_in,
                              void* d_out, int out_size, void* d_ws, size_t ws_size,
                              hipStream_t stream) {
  (void)in_sizes; (void)n_in; (void)out_size; (void)ws_size;

  const float* ch   = (const float*)d_in[0];   // [BATCH, NV] f32
  const float* wts  = (const float*)d_in[1];   // [NITER, 1] f32
  const int*  Hcols = (const int*)d_in[3];     // [NE] i32
  float* out = (float*)d_out;

  char* ws = (char*)d_ws;
  int*            cnt     = (int*)(ws + 0);                  // 32768 B
  unsigned short* v2e_tmp = (unsigned short*)(ws + 32768);   // 49152 B
  unsigned short* cslot   = (unsigned short*)(ws + 81920);   // 49152 B
  unsigned int*   slotp   = (unsigned int*)(ws + 131072);    // 49152 B
  // total ws use: 180224 B

  hipMemsetAsync(cnt, 0, NV * sizeof(int), stream);
  build_v2e<<<(NE + 255) / 256, 256, 0, stream>>>(Hcols, cnt, v2e_tmp);
  invert_slots<<<(NV + 255) / 256, 256, 0, stream>>>(v2e_tmp, cslot);
  greedy_schedule<<<NC / 64, 64, 0, stream>>>(cslot, slotp);

  decode_kernel<<<BATCH, 1024, 0, stream>>>(ch, wts, slotp, out);
}

// Round 7
// 148.265 us; speedup vs baseline: 1.1910x; 1.0952x over previous
//
#include <hip/hip_runtime.h>
#include <stdint.h>

// Problem constants (fixed by the reference)
#define NV    8192   // variables
#define NC    4096   // checks
#define DC    6      // edges per check
#define DV    3      // edges per variable
#define NE    24576  // edges
#define NITER 5
#define BATCH 2048

// ---------------------------------------------------------------------------
// Setup 1: per-var edge lists (sorted ascending so the np.add.at association
// and slot ranks are deterministic).
// ---------------------------------------------------------------------------

__global__ void build_v2e(const int* __restrict__ cols, int* __restrict__ cnt,
                          unsigned short* __restrict__ v2e_tmp) {
  int e = blockIdx.x * blockDim.x + threadIdx.x;
  if (e >= NE) return;
  int v = cols[e];
  int s = atomicAdd(&cnt[v], 1);
  v2e_tmp[v * DV + s] = (unsigned short)e;
}

// Setup 2: per-edge slot codes, contiguous per check: cslot[e] = k*NV + v,
// where k = rank of edge e among its var's ascending edges. (e = c*6 + j.)
__global__ void invert_slots(const unsigned short* __restrict__ v2e_tmp,
                             unsigned short* __restrict__ cslot) {
  int v = blockIdx.x * blockDim.x + threadIdx.x;
  if (v >= NV) return;
  int a = v2e_tmp[v * 3 + 0];
  int b = v2e_tmp[v * 3 + 1];
  int c = v2e_tmp[v * 3 + 2];
  int t;
  if (a > b) { t = a; a = b; b = t; }
  if (b > c) { t = b; b = c; c = t; }
  if (a > b) { t = a; a = b; b = t; }
  cslot[a] = (unsigned short)(0 * NV + v);
  cslot[b] = (unsigned short)(1 * NV + v);
  cslot[c] = (unsigned short)(2 * NV + v);
}

// ---------------------------------------------------------------------------
// Setup 3: QUARTER-granular bank schedule (model validated in R6: lanes of the
// same 16-lane quarter hitting the same bank serialize; cross-quarter aliasing
// is free). Objective: per row j and quarter q, <=1 lane per bank.
// Stage 1: strict auction (claim a FREE bank in your quarter, rotated scan),
//          relaxed fallback (min-count unused candidate).
// Stage 2: ONE pass of row-pair swap improvement (R6 used 8 passes; the extra
//          passes cost ~20us of serial setup for ~2us of decode gain).
// Any per-check edge permutation is BIT-EXACT for the decoder (check update
// is order-symmetric), so scheduler races never affect d_out.
// ---------------------------------------------------------------------------

__device__ __forceinline__ int qc(int n) { return (n > 1) ? (n - 1) : 0; }

__global__ __launch_bounds__(64) void greedy_schedule(
    const unsigned short* __restrict__ cslot, unsigned int* __restrict__ slotp) {
  __shared__ unsigned short sl[64][6];
  __shared__ unsigned char perm[64][6];
  __shared__ int cnt[6][4][32];   // row, quarter, bank

  const int l = threadIdx.x;
  const int q = l >> 4;
  const int c = blockIdx.x * 64 + l;

  const unsigned int* cs32 = (const unsigned int*)cslot;
  unsigned int a0 = cs32[c * 3 + 0];
  unsigned int a1 = cs32[c * 3 + 1];
  unsigned int a2 = cs32[c * 3 + 2];
  sl[l][0] = (unsigned short)(a0 & 0xffffu); sl[l][1] = (unsigned short)(a0 >> 16);
  sl[l][2] = (unsigned short)(a1 & 0xffffu); sl[l][3] = (unsigned short)(a1 >> 16);
  sl[l][4] = (unsigned short)(a2 & 0xffffu); sl[l][5] = (unsigned short)(a2 >> 16);

  for (int t = l; t < 6 * 4 * 32; t += 64) ((int*)cnt)[t] = 0;
  __syncthreads();

  // ---- Stage 1: strict (free-bank-in-quarter) auction, relaxed fallback ---
  unsigned int used = 0;
  for (int j = 0; j < 6; ++j) {
    int placed = -1;
    for (int kk = 0; kk < 6; ++kk) {
      int k = (kk + l) % 6;              // decorrelate lane scan order
      if (used & (1u << k)) continue;
      int bk = sl[l][k] & 31;
      if (atomicAdd(&cnt[j][q][bk], 1) == 0) { placed = k; break; }
      atomicSub(&cnt[j][q][bk], 1);
    }
    if (placed < 0) {                    // relaxed: min-count unused candidate
      int bc = 1 << 30;
      for (int k = 0; k < 6; ++k) {
        if (used & (1u << k)) continue;
        int cc = cnt[j][q][sl[l][k] & 31];
        if (cc < bc) { bc = cc; placed = k; }
      }
      atomicAdd(&cnt[j][q][sl[l][placed] & 31], 1);
    }
    used |= (1u << placed);
    perm[l][j] = (unsigned char)placed;
    __syncthreads();
  }

  // ---- Stage 2: ONE quarter-cost swap-improvement pass --------------------
  for (int j1 = 0; j1 < 6; ++j1) {
    for (int j2 = j1 + 1; j2 < 6; ++j2) {
      int k1 = perm[l][j1], k2 = perm[l][j2];
      int b1 = sl[l][k1] & 31, b2 = sl[l][k2] & 31;
      if (b1 != b2) {
        int c11 = cnt[j1][q][b1], c12 = cnt[j1][q][b2];
        int c21 = cnt[j2][q][b1], c22 = cnt[j2][q][b2];
        int dOld = qc(c11) + qc(c12) + qc(c21) + qc(c22);
        int dNew = qc(c11 - 1) + qc(c12 + 1) + qc(c21 + 1) + qc(c22 - 1);
        if (dNew < dOld) {
          atomicSub(&cnt[j1][q][b1], 1); atomicAdd(&cnt[j1][q][b2], 1);
          atomicSub(&cnt[j2][q][b2], 1); atomicAdd(&cnt[j2][q][b1], 1);
          perm[l][j1] = (unsigned char)k2; perm[l][j2] = (unsigned char)k1;
        }
      }
      __syncthreads();
    }
  }

  unsigned short pm[6];
#pragma unroll
  for (int j = 0; j < 6; ++j) pm[j] = sl[l][perm[l][j]];
  slotp[0 * NC + c] = (unsigned int)pm[0] | ((unsigned int)pm[1] << 16);
  slotp[1 * NC + c] = (unsigned int)pm[2] | ((unsigned int)pm[3] << 16);
  slotp[2 * NC + c] = (unsigned int)pm[4] | ((unsigned int)pm[5] << 16);
}

// ---------------------------------------------------------------------------
// Fused decoder (R4/R6-verbatim): one workgroup per batch element; 96 KB
// var-major slot array. Phase A (float4, contiguous): c2v -> v2c = vl - c2v.
// Phase B (random, bank-scheduled rows, reg-preloaded addrs): v2c -> c2v.
// ---------------------------------------------------------------------------

__global__ __launch_bounds__(1024) void decode_kernel(
    const float* __restrict__ ch, const float* __restrict__ wts,
    const unsigned int* __restrict__ slotp, float* __restrict__ out) {
  __shared__ float s_msg[NE];   // 96 KB

  const int tid = threadIdx.x;
  const int b = blockIdx.x;
  const float* chrow = ch + (size_t)b * NV;
  const float4* ch4 = (const float4*)chrow;

  float4 chreg[2];
  chreg[0] = ch4[tid];           // vars 4*tid .. 4*tid+3
  chreg[1] = ch4[1024 + tid];    // vars 4096+4*tid ..

  float w[NITER];
#pragma unroll
  for (int i = 0; i < NITER; ++i) w[i] = wts[i];

  // Preload the 6 (scheduled) slot indices for each of this thread's 4 checks.
  int idx[4][6];
#pragma unroll
  for (int r = 0; r < 4; ++r) {
    int c = tid + r * 1024;
    unsigned int p0 = slotp[c];
    unsigned int p1 = slotp[NC + c];
    unsigned int p2 = slotp[2 * NC + c];
    idx[r][0] = (int)(p0 & 0xFFFFu); idx[r][1] = (int)(p0 >> 16);
    idx[r][2] = (int)(p1 & 0xFFFFu); idx[r][3] = (int)(p1 >> 16);
    idx[r][4] = (int)(p2 & 0xFFFFu); idx[r][5] = (int)(p2 >> 16);
  }

  float4* m0 = (float4*)&s_msg[0];
  float4* m1 = (float4*)&s_msg[NV];
  float4* m2 = (float4*)&s_msg[2 * NV];

  // ---- it=0 Phase A: c2v==0 -> v2c = ch in all 3 planes -------------------
#pragma unroll
  for (int p = 0; p < 2; ++p) {
    int i4 = p * 1024 + tid;
    float4 v = chreg[p];
    m0[i4] = v; m1[i4] = v; m2[i4] = v;
  }
  __syncthreads();

  for (int it = 0; it < NITER; ++it) {
    const float wi = w[it];

    // ---- Phase B: check update; slots v2c -> c2v --------------------------
#pragma unroll
    for (int r = 0; r < 4; ++r) {
      unsigned int u[6];
      float m1v = INFINITY, m2v = INFINITY;
      unsigned int xs = 0u;
#pragma unroll
      for (int j = 0; j < 6; ++j) {
        float t = s_msg[idx[r][j]];
        unsigned int uu = __float_as_uint(t);
        u[j] = uu;
        xs ^= uu;
        float a = fabsf(t);
        m2v = fminf(m2v, fmaxf(m1v, a));   // uses OLD m1v: exact 2nd-min
        m1v = fminf(m1v, a);
      }
      const bool anyz = (m1v == 0.0f);
      const float m1w = m1v * wi;
      const float m2w = m2v * wi;
#pragma unroll
      for (int j = 0; j < 6; ++j) {
        float a = __uint_as_float(u[j] & 0x7FFFFFFFu);
        float mag = (a == m1v) ? m2w : m1w;  // ties: m2v==m1v, matches ref
        unsigned int s = (xs ^ u[j]) & 0x80000000u;
        float o = __uint_as_float(__float_as_uint(mag) ^ s);
        if (anyz) o = 0.0f;
        s_msg[idx[r][j]] = o;
      }
    }
    __syncthreads();

    // ---- Phase A: variable update; slots c2v -> v2c (float4) --------------
    if (it < NITER - 1) {
#pragma unroll
      for (int p = 0; p < 2; ++p) {
        int i4 = p * 1024 + tid;
        float4 c0 = m0[i4], c1 = m1[i4], c2 = m2[i4];
        float4 cr = chreg[p];
        float4 vl;
        vl.x = cr.x + ((c0.x + c1.x) + c2.x);   // np.add.at association
        vl.y = cr.y + ((c0.y + c1.y) + c2.y);
        vl.z = cr.z + ((c0.z + c1.z) + c2.z);
        vl.w = cr.w + ((c0.w + c1.w) + c2.w);
        float4 o0 = {vl.x - c0.x, vl.y - c0.y, vl.z - c0.z, vl.w - c0.w};
        float4 o1 = {vl.x - c1.x, vl.y - c1.y, vl.z - c1.z, vl.w - c1.w};
        float4 o2 = {vl.x - c2.x, vl.y - c2.y, vl.z - c2.z, vl.w - c2.w};
        m0[i4] = o0; m1[i4] = o1; m2[i4] = o2;
      }
      __syncthreads();
    }
  }

  // ---- Final: out = ch + ((c0+c1)+c2), float4 stores ----------------------
  float4* orow4 = (float4*)(out + (size_t)b * NV);
#pragma unroll
  for (int p = 0; p < 2; ++p) {
    int i4 = p * 1024 + tid;
    float4 c0 = m0[i4], c1 = m1[i4], c2 = m2[i4];
    float4 cr = chreg[p];
    float4 o;
    o.x = cr.x + ((c0.x + c1.x) + c2.x);
    o.y = cr.y + ((c0.y + c1.y) + c2.y);
    o.z = cr.z + ((c0.z + c1.z) + c2.z);
    o.w = cr.w + ((c0.w + c1.w) + c2.w);
    orow4[i4] = o;
  }
}

// ---------------------------------------------------------------------------

extern "C" void kernel_launch(void* const* d_in, const int* in_sizes, int n_in,
                              void* d_out, int out_size, void* d_ws, size_t ws_size,
                              hipStream_t stream) {
  (void)in_sizes; (void)n_in; (void)out_size; (void)ws_size;

  const float* ch   = (const float*)d_in[0];   // [BATCH, NV] f32
  const float* wts  = (const float*)d_in[1];   // [NITER, 1] f32
  const int*  Hcols = (const int*)d_in[3];     // [NE] i32
  float* out = (float*)d_out;

  char* ws = (char*)d_ws;
  int*            cnt     = (int*)(ws + 0);                  // 32768 B
  unsigned short* v2e_tmp = (unsigned short*)(ws + 32768);   // 49152 B
  unsigned short* cslot   = (unsigned short*)(ws + 81920);   // 49152 B
  unsigned int*   slotp   = (unsigned int*)(ws + 131072);    // 49152 B
  // total ws use: 180224 B

  hipMemsetAsync(cnt, 0, NV * sizeof(int), stream);
  build_v2e<<<(NE + 255) / 256, 256, 0, stream>>>(Hcols, cnt, v2e_tmp);
  invert_slots<<<(NV + 255) / 256, 256, 0, stream>>>(v2e_tmp, cslot);
  greedy_schedule<<<NC / 64, 64, 0, stream>>>(cslot, slotp);

  decode_kernel<<<BATCH, 1024, 0, stream>>>(ch, wts, slotp, out);
}

// Round 8
// 147.021 us; speedup vs baseline: 1.2011x; 1.0085x over previous
//
#include <hip/hip_runtime.h>
#include <stdint.h>

// Problem constants (fixed by the reference)
#define NV    8192   // variables
#define NC    4096   // checks
#define DC    6      // edges per check
#define DV    3      // edges per variable
#define NE    24576  // edges
#define NITER 5
#define BATCH 2048

// ---------------------------------------------------------------------------
// Setup 1: per-var edge lists (sorted ascending so the np.add.at association
// and slot ranks are deterministic).
// ---------------------------------------------------------------------------

__global__ void build_v2e(const int* __restrict__ cols, int* __restrict__ cnt,
                          unsigned short* __restrict__ v2e_tmp) {
  int e = blockIdx.x * blockDim.x + threadIdx.x;
  if (e >= NE) return;
  int v = cols[e];
  int s = atomicAdd(&cnt[v], 1);
  v2e_tmp[v * DV + s] = (unsigned short)e;
}

// Setup 2: per-edge slot codes, contiguous per check: cslot[e] = k*NV + v,
// where k = rank of edge e among its var's ascending edges. (e = c*6 + j.)
__global__ void invert_slots(const unsigned short* __restrict__ v2e_tmp,
                             unsigned short* __restrict__ cslot) {
  int v = blockIdx.x * blockDim.x + threadIdx.x;
  if (v >= NV) return;
  int a = v2e_tmp[v * 3 + 0];
  int b = v2e_tmp[v * 3 + 1];
  int c = v2e_tmp[v * 3 + 2];
  int t;
  if (a > b) { t = a; a = b; b = t; }
  if (b > c) { t = b; b = c; c = t; }
  if (a > b) { t = a; a = b; b = t; }
  cslot[a] = (unsigned short)(0 * NV + v);
  cslot[b] = (unsigned short)(1 * NV + v);
  cslot[c] = (unsigned short)(2 * NV + v);
}

// ---------------------------------------------------------------------------
// Setup 3: QUARTER-granular bank schedule (model validated in R6: lanes of the
// same 16-lane quarter hitting the same bank serialize; cross-quarter aliasing
// is free). Objective: per row j and quarter q, <=1 lane per bank.
// Stage 0: per-quarter histogram of the 96 candidate banks.
// Stage 1: MOST-CONSTRAINED-FIRST auction — each lane scans its candidates in
//          descending contention order; a degree-d bank's owners keep retrying
//          it until placed, spreading it across d distinct rows.
// Stage 2: ONE pass of row-pair swap improvement.
// Any per-check edge permutation is BIT-EXACT for the decoder (check update
// is order-symmetric), so scheduler races never affect d_out.
// ---------------------------------------------------------------------------

__device__ __forceinline__ int qc(int n) { return (n > 1) ? (n - 1) : 0; }

__global__ __launch_bounds__(64) void greedy_schedule(
    const unsigned short* __restrict__ cslot, unsigned int* __restrict__ slotp) {
  __shared__ unsigned short sl[64][6];
  __shared__ unsigned char perm[64][6];
  __shared__ int qhist[4][32];    // quarter, bank: candidate contention
  __shared__ int cnt[6][4][32];   // row, quarter, bank

  const int l = threadIdx.x;
  const int q = l >> 4;
  const int c = blockIdx.x * 64 + l;

  const unsigned int* cs32 = (const unsigned int*)cslot;
  unsigned int a0 = cs32[c * 3 + 0];
  unsigned int a1 = cs32[c * 3 + 1];
  unsigned int a2 = cs32[c * 3 + 2];
  sl[l][0] = (unsigned short)(a0 & 0xffffu); sl[l][1] = (unsigned short)(a0 >> 16);
  sl[l][2] = (unsigned short)(a1 & 0xffffu); sl[l][3] = (unsigned short)(a1 >> 16);
  sl[l][4] = (unsigned short)(a2 & 0xffffu); sl[l][5] = (unsigned short)(a2 >> 16);

  int bank[6];
#pragma unroll
  for (int k = 0; k < 6; ++k) bank[k] = sl[l][k] & 31;

  for (int t = l; t < 128; t += 64) ((int*)qhist)[t] = 0;
  for (int t = l; t < 768; t += 64) ((int*)cnt)[t] = 0;
  __syncthreads();

#pragma unroll
  for (int k = 0; k < 6; ++k) atomicAdd(&qhist[q][bank[k]], 1);
  __syncthreads();

  // ---- per-lane candidate order: contention descending (15-CE network) ----
  int key[6];
#pragma unroll
  for (int k = 0; k < 6; ++k) key[k] = (qhist[q][bank[k]] << 3) | k;
#pragma unroll
  for (int i = 0; i < 5; ++i) {
#pragma unroll
    for (int j2 = 0; j2 < 5 - i; ++j2) {
      if (key[j2] < key[j2 + 1]) {
        int t = key[j2]; key[j2] = key[j2 + 1]; key[j2 + 1] = t;
      }
    }
  }

  // ---- Stage 1: hardest-first strict auction, relaxed fallback ------------
  unsigned int used = 0;
  for (int j = 0; j < 6; ++j) {
    int placed = -1;
    for (int s = 0; s < 6; ++s) {
      int k = key[s] & 7;
      if (used & (1u << k)) continue;
      int bk = bank[k];
      if (cnt[j][q][bk] == 0) {
        if (atomicAdd(&cnt[j][q][bk], 1) == 0) { placed = k; break; }
        atomicSub(&cnt[j][q][bk], 1);
      }
    }
    if (placed < 0) {                    // relaxed: min-count unused candidate
      int bc = 1 << 30;
      for (int k = 0; k < 6; ++k) {
        if (used & (1u << k)) continue;
        int cc = cnt[j][q][bank[k]];
        if (cc < bc) { bc = cc; placed = k; }
      }
      atomicAdd(&cnt[j][q][bank[placed]], 1);
    }
    used |= (1u << placed);
    perm[l][j] = (unsigned char)placed;
    __syncthreads();
  }

  // ---- Stage 2: ONE quarter-cost swap-improvement pass --------------------
  for (int j1 = 0; j1 < 6; ++j1) {
    for (int j2 = j1 + 1; j2 < 6; ++j2) {
      int k1 = perm[l][j1], k2 = perm[l][j2];
      int b1 = bank[k1], b2 = bank[k2];
      if (b1 != b2) {
        int c11 = cnt[j1][q][b1], c12 = cnt[j1][q][b2];
        int c21 = cnt[j2][q][b1], c22 = cnt[j2][q][b2];
        int dOld = qc(c11) + qc(c12) + qc(c21) + qc(c22);
        int dNew = qc(c11 - 1) + qc(c12 + 1) + qc(c21 + 1) + qc(c22 - 1);
        if (dNew < dOld) {
          atomicSub(&cnt[j1][q][b1], 1); atomicAdd(&cnt[j1][q][b2], 1);
          atomicSub(&cnt[j2][q][b2], 1); atomicAdd(&cnt[j2][q][b1], 1);
          perm[l][j1] = (unsigned char)k2; perm[l][j2] = (unsigned char)k1;
        }
      }
      __syncthreads();
    }
  }

  unsigned short pm[6];
#pragma unroll
  for (int j = 0; j < 6; ++j) pm[j] = sl[l][perm[l][j]];
  slotp[0 * NC + c] = (unsigned int)pm[0] | ((unsigned int)pm[1] << 16);
  slotp[1 * NC + c] = (unsigned int)pm[2] | ((unsigned int)pm[3] << 16);
  slotp[2 * NC + c] = (unsigned int)pm[4] | ((unsigned int)pm[5] << 16);
}

// ---------------------------------------------------------------------------
// Fused decoder (R4/R6/R7-verbatim): one workgroup per batch element; 96 KB
// var-major slot array. Phase A (float4, contiguous): c2v -> v2c = vl - c2v.
// Phase B (random, bank-scheduled rows, reg-preloaded addrs): v2c -> c2v.
// ---------------------------------------------------------------------------

__global__ __launch_bounds__(1024) void decode_kernel(
    const float* __restrict__ ch, const float* __restrict__ wts,
    const unsigned int* __restrict__ slotp, float* __restrict__ out) {
  __shared__ float s_msg[NE];   // 96 KB

  const int tid = threadIdx.x;
  const int b = blockIdx.x;
  const float* chrow = ch + (size_t)b * NV;
  const float4* ch4 = (const float4*)chrow;

  float4 chreg[2];
  chreg[0] = ch4[tid];           // vars 4*tid .. 4*tid+3
  chreg[1] = ch4[1024 + tid];    // vars 4096+4*tid ..

  float w[NITER];
#pragma unroll
  for (int i = 0; i < NITER; ++i) w[i] = wts[i];

  // Preload the 6 (scheduled) slot indices for each of this thread's 4 checks.
  int idx[4][6];
#pragma unroll
  for (int r = 0; r < 4; ++r) {
    int c = tid + r * 1024;
    unsigned int p0 = slotp[c];
    unsigned int p1 = slotp[NC + c];
    unsigned int p2 = slotp[2 * NC + c];
    idx[r][0] = (int)(p0 & 0xFFFFu); idx[r][1] = (int)(p0 >> 16);
    idx[r][2] = (int)(p1 & 0xFFFFu); idx[r][3] = (int)(p1 >> 16);
    idx[r][4] = (int)(p2 & 0xFFFFu); idx[r][5] = (int)(p2 >> 16);
  }

  float4* m0 = (float4*)&s_msg[0];
  float4* m1 = (float4*)&s_msg[NV];
  float4* m2 = (float4*)&s_msg[2 * NV];

  // ---- it=0 Phase A: c2v==0 -> v2c = ch in all 3 planes -------------------
#pragma unroll
  for (int p = 0; p < 2; ++p) {
    int i4 = p * 1024 + tid;
    float4 v = chreg[p];
    m0[i4] = v; m1[i4] = v; m2[i4] = v;
  }
  __syncthreads();

  for (int it = 0; it < NITER; ++it) {
    const float wi = w[it];

    // ---- Phase B: check update; slots v2c -> c2v --------------------------
#pragma unroll
    for (int r = 0; r < 4; ++r) {
      unsigned int u[6];
      float m1v = INFINITY, m2v = INFINITY;
      unsigned int xs = 0u;
#pragma unroll
      for (int j = 0; j < 6; ++j) {
        float t = s_msg[idx[r][j]];
        unsigned int uu = __float_as_uint(t);
        u[j] = uu;
        xs ^= uu;
        float a = fabsf(t);
        m2v = fminf(m2v, fmaxf(m1v, a));   // uses OLD m1v: exact 2nd-min
        m1v = fminf(m1v, a);
      }
      const bool anyz = (m1v == 0.0f);
      const float m1w = m1v * wi;
      const float m2w = m2v * wi;
#pragma unroll
      for (int j = 0; j < 6; ++j) {
        float a = __uint_as_float(u[j] & 0x7FFFFFFFu);
        float mag = (a == m1v) ? m2w : m1w;  // ties: m2v==m1v, matches ref
        unsigned int s = (xs ^ u[j]) & 0x80000000u;
        float o = __uint_as_float(__float_as_uint(mag) ^ s);
        if (anyz) o = 0.0f;
        s_msg[idx[r][j]] = o;
      }
    }
    __syncthreads();

    // ---- Phase A: variable update; slots c2v -> v2c (float4) --------------
    if (it < NITER - 1) {
#pragma unroll
      for (int p = 0; p < 2; ++p) {
        int i4 = p * 1024 + tid;
        float4 c0 = m0[i4], c1 = m1[i4], c2 = m2[i4];
        float4 cr = chreg[p];
        float4 vl;
        vl.x = cr.x + ((c0.x + c1.x) + c2.x);   // np.add.at association
        vl.y = cr.y + ((c0.y + c1.y) + c2.y);
        vl.z = cr.z + ((c0.z + c1.z) + c2.z);
        vl.w = cr.w + ((c0.w + c1.w) + c2.w);
        float4 o0 = {vl.x - c0.x, vl.y - c0.y, vl.z - c0.z, vl.w - c0.w};
        float4 o1 = {vl.x - c1.x, vl.y - c1.y, vl.z - c1.z, vl.w - c1.w};
        float4 o2 = {vl.x - c2.x, vl.y - c2.y, vl.z - c2.z, vl.w - c2.w};
        m0[i4] = o0; m1[i4] = o1; m2[i4] = o2;
      }
      __syncthreads();
    }
  }

  // ---- Final: out = ch + ((c0+c1)+c2), float4 stores ----------------------
  float4* orow4 = (float4*)(out + (size_t)b * NV);
#pragma unroll
  for (int p = 0; p < 2; ++p) {
    int i4 = p * 1024 + tid;
    float4 c0 = m0[i4], c1 = m1[i4], c2 = m2[i4];
    float4 cr = chreg[p];
    float4 o;
    o.x = cr.x + ((c0.x + c1.x) + c2.x);
    o.y = cr.y + ((c0.y + c1.y) + c2.y);
    o.z = cr.z + ((c0.z + c1.z) + c2.z);
    o.w = cr.w + ((c0.w + c1.w) + c2.w);
    orow4[i4] = o;
  }
}

// ---------------------------------------------------------------------------

extern "C" void kernel_launch(void* const* d_in, const int* in_sizes, int n_in,
                              void* d_out, int out_size, void* d_ws, size_t ws_size,
                              hipStream_t stream) {
  (void)in_sizes; (void)n_in; (void)out_size; (void)ws_size;

  const float* ch   = (const float*)d_in[0];   // [BATCH, NV] f32
  const float* wts  = (const float*)d_in[1];   // [NITER, 1] f32
  const int*  Hcols = (const int*)d_in[3];     // [NE] i32
  float* out = (float*)d_out;

  char* ws = (char*)d_ws;
  int*            cnt     = (int*)(ws + 0);                  // 32768 B
  unsigned short* v2e_tmp = (unsigned short*)(ws + 32768);   // 49152 B
  unsigned short* cslot   = (unsigned short*)(ws + 81920);   // 49152 B
  unsigned int*   slotp   = (unsigned int*)(ws + 131072);    // 49152 B
  // total ws use: 180224 B

  hipMemsetAsync(cnt, 0, NV * sizeof(int), stream);
  build_v2e<<<(NE + 255) / 256, 256, 0, stream>>>(Hcols, cnt, v2e_tmp);
  invert_slots<<<(NV + 255) / 256, 256, 0, stream>>>(v2e_tmp, cslot);
  greedy_schedule<<<NC / 64, 64, 0, stream>>>(cslot, slotp);

  decode_kernel<<<BATCH, 1024, 0, stream>>>(ch, wts, slotp, out);
}

// Round 9
// 146.018 us; speedup vs baseline: 1.2094x; 1.0069x over previous
//
#include <hip/hip_runtime.h>
#include <stdint.h>

// Problem constants (fixed by the reference)
#define NV    8192   // variables
#define NC    4096   // checks
#define DC    6      // edges per check
#define DV    3      // edges per variable
#define NE    24576  // edges
#define NITER 5
#define BATCH 2048

// ---------------------------------------------------------------------------
// Setup 1: per-var edge lists (sorted ascending so the np.add.at association
// and slot ranks are deterministic).
// ---------------------------------------------------------------------------

__global__ void build_v2e(const int* __restrict__ cols, int* __restrict__ cnt,
                          unsigned short* __restrict__ v2e_tmp) {
  int e = blockIdx.x * blockDim.x + threadIdx.x;
  if (e >= NE) return;
  int v = cols[e];
  int s = atomicAdd(&cnt[v], 1);
  v2e_tmp[v * DV + s] = (unsigned short)e;
}

// Setup 2: per-edge slot codes, contiguous per check: cslot[e] = k*NV + v,
// where k = rank of edge e among its var's ascending edges. (e = c*6 + j.)
__global__ void invert_slots(const unsigned short* __restrict__ v2e_tmp,
                             unsigned short* __restrict__ cslot) {
  int v = blockIdx.x * blockDim.x + threadIdx.x;
  if (v >= NV) return;
  int a = v2e_tmp[v * 3 + 0];
  int b = v2e_tmp[v * 3 + 1];
  int c = v2e_tmp[v * 3 + 2];
  int t;
  if (a > b) { t = a; a = b; b = t; }
  if (b > c) { t = b; b = c; c = t; }
  if (a > b) { t = a; a = b; b = t; }
  cslot[a] = (unsigned short)(0 * NV + v);
  cslot[b] = (unsigned short)(1 * NV + v);
  cslot[c] = (unsigned short)(2 * NV + v);
}

// ---------------------------------------------------------------------------
// Setup 3: QUARTER-granular bank schedule (R8-verbatim). Lanes of the same
// 16-lane quarter hitting the same bank serialize; cross-quarter is free.
// Objective: per row j and quarter q, <=1 lane per bank (bank = var & 31,
// identical for the vl-read and the c2v-write of the same edge).
// Any per-check edge permutation is BIT-EXACT for the decoder (check update
// is order-symmetric), so scheduler races never affect d_out.
// ---------------------------------------------------------------------------

__device__ __forceinline__ int qc(int n) { return (n > 1) ? (n - 1) : 0; }

__global__ __launch_bounds__(64) void greedy_schedule(
    const unsigned short* __restrict__ cslot, unsigned int* __restrict__ slotp) {
  __shared__ unsigned short sl[64][6];
  __shared__ unsigned char perm[64][6];
  __shared__ int qhist[4][32];    // quarter, bank: candidate contention
  __shared__ int cnt[6][4][32];   // row, quarter, bank

  const int l = threadIdx.x;
  const int q = l >> 4;
  const int c = blockIdx.x * 64 + l;

  const unsigned int* cs32 = (const unsigned int*)cslot;
  unsigned int a0 = cs32[c * 3 + 0];
  unsigned int a1 = cs32[c * 3 + 1];
  unsigned int a2 = cs32[c * 3 + 2];
  sl[l][0] = (unsigned short)(a0 & 0xffffu); sl[l][1] = (unsigned short)(a0 >> 16);
  sl[l][2] = (unsigned short)(a1 & 0xffffu); sl[l][3] = (unsigned short)(a1 >> 16);
  sl[l][4] = (unsigned short)(a2 & 0xffffu); sl[l][5] = (unsigned short)(a2 >> 16);

  int bank[6];
#pragma unroll
  for (int k = 0; k < 6; ++k) bank[k] = sl[l][k] & 31;

  for (int t = l; t < 128; t += 64) ((int*)qhist)[t] = 0;
  for (int t = l; t < 768; t += 64) ((int*)cnt)[t] = 0;
  __syncthreads();

#pragma unroll
  for (int k = 0; k < 6; ++k) atomicAdd(&qhist[q][bank[k]], 1);
  __syncthreads();

  // ---- per-lane candidate order: contention descending (15-CE network) ----
  int key[6];
#pragma unroll
  for (int k = 0; k < 6; ++k) key[k] = (qhist[q][bank[k]] << 3) | k;
#pragma unroll
  for (int i = 0; i < 5; ++i) {
#pragma unroll
    for (int j2 = 0; j2 < 5 - i; ++j2) {
      if (key[j2] < key[j2 + 1]) {
        int t = key[j2]; key[j2] = key[j2 + 1]; key[j2 + 1] = t;
      }
    }
  }

  // ---- Stage 1: hardest-first strict auction, relaxed fallback ------------
  unsigned int used = 0;
  for (int j = 0; j < 6; ++j) {
    int placed = -1;
    for (int s = 0; s < 6; ++s) {
      int k = key[s] & 7;
      if (used & (1u << k)) continue;
      int bk = bank[k];
      if (cnt[j][q][bk] == 0) {
        if (atomicAdd(&cnt[j][q][bk], 1) == 0) { placed = k; break; }
        atomicSub(&cnt[j][q][bk], 1);
      }
    }
    if (placed < 0) {                    // relaxed: min-count unused candidate
      int bc = 1 << 30;
      for (int k = 0; k < 6; ++k) {
        if (used & (1u << k)) continue;
        int cc = cnt[j][q][bank[k]];
        if (cc < bc) { bc = cc; placed = k; }
      }
      atomicAdd(&cnt[j][q][bank[placed]], 1);
    }
    used |= (1u << placed);
    perm[l][j] = (unsigned char)placed;
    __syncthreads();
  }

  // ---- Stage 2: ONE quarter-cost swap-improvement pass --------------------
  for (int j1 = 0; j1 < 6; ++j1) {
    for (int j2 = j1 + 1; j2 < 6; ++j2) {
      int k1 = perm[l][j1], k2 = perm[l][j2];
      int b1 = bank[k1], b2 = bank[k2];
      if (b1 != b2) {
        int c11 = cnt[j1][q][b1], c12 = cnt[j1][q][b2];
        int c21 = cnt[j2][q][b1], c22 = cnt[j2][q][b2];
        int dOld = qc(c11) + qc(c12) + qc(c21) + qc(c22);
        int dNew = qc(c11 - 1) + qc(c12 + 1) + qc(c21 + 1) + qc(c22 - 1);
        if (dNew < dOld) {
          atomicSub(&cnt[j1][q][b1], 1); atomicAdd(&cnt[j1][q][b2], 1);
          atomicSub(&cnt[j2][q][b2], 1); atomicAdd(&cnt[j2][q][b1], 1);
          perm[l][j1] = (unsigned char)k2; perm[l][j2] = (unsigned char)k1;
        }
      }
      __syncthreads();
    }
  }

  unsigned short pm[6];
#pragma unroll
  for (int j = 0; j < 6; ++j) pm[j] = sl[l][perm[l][j]];
  slotp[0 * NC + c] = (unsigned int)pm[0] | ((unsigned int)pm[1] << 16);
  slotp[1 * NC + c] = (unsigned int)pm[2] | ((unsigned int)pm[3] << 16);
  slotp[2 * NC + c] = (unsigned int)pm[4] | ((unsigned int)pm[5] << 16);
}

// ---------------------------------------------------------------------------
// Fused decoder: one workgroup per batch element.
// LDS: 3 c2v planes (var-major, 96 KB) + 1 vl plane (32 KB) = 128 KB.
// c2v additionally lives in the owning check-thread's REGISTERS, so:
//   Phase A: read 3 c2v planes + write 1 vl plane (4 wide ops, was 12).
//   Phase B: 6 random vl reads + 6 random c2v writes (self-exclusion from
//            registers; bit-identical, register holds exactly what was stored).
// ---------------------------------------------------------------------------

__global__ __launch_bounds__(1024) void decode_kernel(
    const float* __restrict__ ch, const float* __restrict__ wts,
    const unsigned int* __restrict__ slotp, float* __restrict__ out) {
  __shared__ float s_msg[NE];   // c2v planes, 96 KB
  __shared__ float s_vl[NV];    // var LLR plane, 32 KB

  const int tid = threadIdx.x;
  const int b = blockIdx.x;
  const float* chrow = ch + (size_t)b * NV;
  const float4* ch4 = (const float4*)chrow;

  float4 chreg[2];
  chreg[0] = ch4[tid];           // vars 4*tid .. 4*tid+3
  chreg[1] = ch4[1024 + tid];    // vars 4096+4*tid ..

  float w[NITER];
#pragma unroll
  for (int i = 0; i < NITER; ++i) w[i] = wts[i];

  // Preload the 6 (scheduled) slot indices for each of this thread's 4 checks.
  int idx[4][6];
#pragma unroll
  for (int r = 0; r < 4; ++r) {
    int c = tid + r * 1024;
    unsigned int p0 = slotp[c];
    unsigned int p1 = slotp[NC + c];
    unsigned int p2 = slotp[2 * NC + c];
    idx[r][0] = (int)(p0 & 0xFFFFu); idx[r][1] = (int)(p0 >> 16);
    idx[r][2] = (int)(p1 & 0xFFFFu); idx[r][3] = (int)(p1 >> 16);
    idx[r][4] = (int)(p2 & 0xFFFFu); idx[r][5] = (int)(p2 >> 16);
  }

  // c2v for this thread's 4 checks, resident in registers across iterations.
  float creg[4][6];
#pragma unroll
  for (int r = 0; r < 4; ++r)
#pragma unroll
    for (int j = 0; j < 6; ++j) creg[r][j] = 0.0f;

  float4* m0 = (float4*)&s_msg[0];
  float4* m1 = (float4*)&s_msg[NV];
  float4* m2 = (float4*)&s_msg[2 * NV];
  float4* vl4 = (float4*)s_vl;

  // ---- init: vl = ch (it0 v2c = vl - 0 = ch) ------------------------------
#pragma unroll
  for (int p = 0; p < 2; ++p) vl4[p * 1024 + tid] = chreg[p];
  __syncthreads();

  for (int it = 0; it < NITER; ++it) {
    const float wi = w[it];

    // ---- Phase B: check update; reads vl, writes c2v (planes + regs) ------
#pragma unroll
    for (int r = 0; r < 4; ++r) {
      unsigned int u[6];
      float m1v = INFINITY, m2v = INFINITY;
      unsigned int xs = 0u;
#pragma unroll
      for (int j = 0; j < 6; ++j) {
        float vlv = s_vl[idx[r][j] & (NV - 1)];
        float t = vlv - creg[r][j];
        unsigned int uu = __float_as_uint(t);
        u[j] = uu;
        xs ^= uu;
        float a = fabsf(t);
        m2v = fminf(m2v, fmaxf(m1v, a));   // uses OLD m1v: exact 2nd-min
        m1v = fminf(m1v, a);
      }
      const bool anyz = (m1v == 0.0f);
      const float m1w = m1v * wi;
      const float m2w = m2v * wi;
#pragma unroll
      for (int j = 0; j < 6; ++j) {
        float a = __uint_as_float(u[j] & 0x7FFFFFFFu);
        float mag = (a == m1v) ? m2w : m1w;  // ties: m2v==m1v, matches ref
        unsigned int s = (xs ^ u[j]) & 0x80000000u;
        float o = __uint_as_float(__float_as_uint(mag) ^ s);
        if (anyz) o = 0.0f;
        creg[r][j] = o;
        s_msg[idx[r][j]] = o;
      }
    }
    __syncthreads();

    // ---- Phase A: vl = ch + ((c0+c1)+c2), one wide write ------------------
    if (it < NITER - 1) {
#pragma unroll
      for (int p = 0; p < 2; ++p) {
        int i4 = p * 1024 + tid;
        float4 c0 = m0[i4], c1 = m1[i4], c2 = m2[i4];
        float4 cr = chreg[p];
        float4 vl;
        vl.x = cr.x + ((c0.x + c1.x) + c2.x);   // np.add.at association
        vl.y = cr.y + ((c0.y + c1.y) + c2.y);
        vl.z = cr.z + ((c0.z + c1.z) + c2.z);
        vl.w = cr.w + ((c0.w + c1.w) + c2.w);
        vl4[i4] = vl;
      }
      __syncthreads();
    }
  }

  // ---- Final: out = ch + ((c0+c1)+c2), float4 stores ----------------------
  float4* orow4 = (float4*)(out + (size_t)b * NV);
#pragma unroll
  for (int p = 0; p < 2; ++p) {
    int i4 = p * 1024 + tid;
    float4 c0 = m0[i4], c1 = m1[i4], c2 = m2[i4];
    float4 cr = chreg[p];
    float4 o;
    o.x = cr.x + ((c0.x + c1.x) + c2.x);
    o.y = cr.y + ((c0.y + c1.y) + c2.y);
    o.z = cr.z + ((c0.z + c1.z) + c2.z);
    o.w = cr.w + ((c0.w + c1.w) + c2.w);
    orow4[i4] = o;
  }
}

// ---------------------------------------------------------------------------

extern "C" void kernel_launch(void* const* d_in, const int* in_sizes, int n_in,
                              void* d_out, int out_size, void* d_ws, size_t ws_size,
                              hipStream_t stream) {
  (void)in_sizes; (void)n_in; (void)out_size; (void)ws_size;

  const float* ch   = (const float*)d_in[0];   // [BATCH, NV] f32
  const float* wts  = (const float*)d_in[1];   // [NITER, 1] f32
  const int*  Hcols = (const int*)d_in[3];     // [NE] i32
  float* out = (float*)d_out;

  char* ws = (char*)d_ws;
  int*            cnt     = (int*)(ws + 0);                  // 32768 B
  unsigned short* v2e_tmp = (unsigned short*)(ws + 32768);   // 49152 B
  unsigned short* cslot   = (unsigned short*)(ws + 81920);   // 49152 B
  unsigned int*   slotp   = (unsigned int*)(ws + 131072);    // 49152 B
  // total ws use: 180224 B

  hipMemsetAsync(cnt, 0, NV * sizeof(int), stream);
  build_v2e<<<(NE + 255) / 256, 256, 0, stream>>>(Hcols, cnt, v2e_tmp);
  invert_slots<<<(NV + 255) / 256, 256, 0, stream>>>(v2e_tmp, cslot);
  greedy_schedule<<<NC / 64, 64, 0, stream>>>(cslot, slotp);

  decode_kernel<<<BATCH, 1024, 0, stream>>>(ch, wts, slotp, out);
}

// Round 10
// 138.589 us; speedup vs baseline: 1.2742x; 1.0536x over previous
//
#include <hip/hip_runtime.h>
#include <stdint.h>

// Problem constants (fixed by the reference)
#define NV    8192   // variables
#define NC    4096   // checks
#define DC    6      // edges per check
#define DV    3      // edges per variable
#define NE    24576  // edges
#define NITER 5
#define BATCH 2048

// ---------------------------------------------------------------------------
// Setup 1: per-var edge lists (sorted ascending so the np.add.at association
// and slot ranks are deterministic).
// ---------------------------------------------------------------------------

__global__ void build_v2e(const int* __restrict__ cols, int* __restrict__ cnt,
                          unsigned short* __restrict__ v2e_tmp) {
  int e = blockIdx.x * blockDim.x + threadIdx.x;
  if (e >= NE) return;
  int v = cols[e];
  int s = atomicAdd(&cnt[v], 1);
  v2e_tmp[v * DV + s] = (unsigned short)e;
}

// Setup 2: per-edge slot codes, contiguous per check: cslot[e] = k*NV + v,
// where k = rank of edge e among its var's ascending edges. (e = c*6 + j.)
__global__ void invert_slots(const unsigned short* __restrict__ v2e_tmp,
                             unsigned short* __restrict__ cslot) {
  int v = blockIdx.x * blockDim.x + threadIdx.x;
  if (v >= NV) return;
  int a = v2e_tmp[v * 3 + 0];
  int b = v2e_tmp[v * 3 + 1];
  int c = v2e_tmp[v * 3 + 2];
  int t;
  if (a > b) { t = a; a = b; b = t; }
  if (b > c) { t = b; b = c; c = t; }
  if (a > b) { t = a; a = b; b = t; }
  cslot[a] = (unsigned short)(0 * NV + v);
  cslot[b] = (unsigned short)(1 * NV + v);
  cslot[c] = (unsigned short)(2 * NV + v);
}

// ---------------------------------------------------------------------------
// Setup 3: QUARTER-granular bank schedule (R8-verbatim). Lanes of the same
// 16-lane quarter hitting the same bank serialize; cross-quarter is free.
// Objective: per row j and quarter q, <=1 lane per bank (bank = var & 31,
// identical for the vl-read and the c2v-write of the same edge).
// Any per-check edge permutation is BIT-EXACT for the decoder (check update
// is order-symmetric), so scheduler races never affect d_out.
// ---------------------------------------------------------------------------

__device__ __forceinline__ int qc(int n) { return (n > 1) ? (n - 1) : 0; }

__global__ __launch_bounds__(64) void greedy_schedule(
    const unsigned short* __restrict__ cslot, unsigned int* __restrict__ slotp) {
  __shared__ unsigned short sl[64][6];
  __shared__ unsigned char perm[64][6];
  __shared__ int qhist[4][32];    // quarter, bank: candidate contention
  __shared__ int cnt[6][4][32];   // row, quarter, bank

  const int l = threadIdx.x;
  const int q = l >> 4;
  const int c = blockIdx.x * 64 + l;

  const unsigned int* cs32 = (const unsigned int*)cslot;
  unsigned int a0 = cs32[c * 3 + 0];
  unsigned int a1 = cs32[c * 3 + 1];
  unsigned int a2 = cs32[c * 3 + 2];
  sl[l][0] = (unsigned short)(a0 & 0xffffu); sl[l][1] = (unsigned short)(a0 >> 16);
  sl[l][2] = (unsigned short)(a1 & 0xffffu); sl[l][3] = (unsigned short)(a1 >> 16);
  sl[l][4] = (unsigned short)(a2 & 0xffffu); sl[l][5] = (unsigned short)(a2 >> 16);

  int bank[6];
#pragma unroll
  for (int k = 0; k < 6; ++k) bank[k] = sl[l][k] & 31;

  for (int t = l; t < 128; t += 64) ((int*)qhist)[t] = 0;
  for (int t = l; t < 768; t += 64) ((int*)cnt)[t] = 0;
  __syncthreads();

#pragma unroll
  for (int k = 0; k < 6; ++k) atomicAdd(&qhist[q][bank[k]], 1);
  __syncthreads();

  // ---- per-lane candidate order: contention descending (15-CE network) ----
  int key[6];
#pragma unroll
  for (int k = 0; k < 6; ++k) key[k] = (qhist[q][bank[k]] << 3) | k;
#pragma unroll
  for (int i = 0; i < 5; ++i) {
#pragma unroll
    for (int j2 = 0; j2 < 5 - i; ++j2) {
      if (key[j2] < key[j2 + 1]) {
        int t = key[j2]; key[j2] = key[j2 + 1]; key[j2 + 1] = t;
      }
    }
  }

  // ---- Stage 1: hardest-first strict auction, relaxed fallback ------------
  unsigned int used = 0;
  for (int j = 0; j < 6; ++j) {
    int placed = -1;
    for (int s = 0; s < 6; ++s) {
      int k = key[s] & 7;
      if (used & (1u << k)) continue;
      int bk = bank[k];
      if (cnt[j][q][bk] == 0) {
        if (atomicAdd(&cnt[j][q][bk], 1) == 0) { placed = k; break; }
        atomicSub(&cnt[j][q][bk], 1);
      }
    }
    if (placed < 0) {                    // relaxed: min-count unused candidate
      int bc = 1 << 30;
      for (int k = 0; k < 6; ++k) {
        if (used & (1u << k)) continue;
        int cc = cnt[j][q][bank[k]];
        if (cc < bc) { bc = cc; placed = k; }
      }
      atomicAdd(&cnt[j][q][bank[placed]], 1);
    }
    used |= (1u << placed);
    perm[l][j] = (unsigned char)placed;
    __syncthreads();
  }

  // ---- Stage 2: ONE quarter-cost swap-improvement pass --------------------
  for (int j1 = 0; j1 < 6; ++j1) {
    for (int j2 = j1 + 1; j2 < 6; ++j2) {
      int k1 = perm[l][j1], k2 = perm[l][j2];
      int b1 = bank[k1], b2 = bank[k2];
      if (b1 != b2) {
        int c11 = cnt[j1][q][b1], c12 = cnt[j1][q][b2];
        int c21 = cnt[j2][q][b1], c22 = cnt[j2][q][b2];
        int dOld = qc(c11) + qc(c12) + qc(c21) + qc(c22);
        int dNew = qc(c11 - 1) + qc(c12 + 1) + qc(c21 + 1) + qc(c22 - 1);
        if (dNew < dOld) {
          atomicSub(&cnt[j1][q][b1], 1); atomicAdd(&cnt[j1][q][b2], 1);
          atomicSub(&cnt[j2][q][b2], 1); atomicAdd(&cnt[j2][q][b1], 1);
          perm[l][j1] = (unsigned char)k2; perm[l][j2] = (unsigned char)k1;
        }
      }
      __syncthreads();
    }
  }

  unsigned short pm[6];
#pragma unroll
  for (int j = 0; j < 6; ++j) pm[j] = sl[l][perm[l][j]];
  slotp[0 * NC + c] = (unsigned int)pm[0] | ((unsigned int)pm[1] << 16);
  slotp[1 * NC + c] = (unsigned int)pm[2] | ((unsigned int)pm[3] << 16);
  slotp[2 * NC + c] = (unsigned int)pm[4] | ((unsigned int)pm[5] << 16);
}

// ---------------------------------------------------------------------------
// Fused decoder: one workgroup per batch element.
// LDS: 3 c2v planes (var-major, 96 KB) + 1 vl plane (32 KB) = 128 KB.
// c2v lives in the owning check-thread's REGISTERS across iterations.
// __launch_bounds__(1024,4): LDS caps us at 1 block/CU = 4 waves/SIMD, so the
// register budget is 128 VGPRs — let the compiler keep idx/vidx/creg resident
// and all 24 Phase-B loads in flight (R9 was squeezed into 64 VGPRs).
// ---------------------------------------------------------------------------

__global__ __launch_bounds__(1024, 4) void decode_kernel(
    const float* __restrict__ ch, const float* __restrict__ wts,
    const unsigned int* __restrict__ slotp, float* __restrict__ out) {
  __shared__ float s_msg[NE];   // c2v planes, 96 KB
  __shared__ float s_vl[NV];    // var LLR plane, 32 KB

  const int tid = threadIdx.x;
  const int b = blockIdx.x;
  const float* chrow = ch + (size_t)b * NV;
  const float4* ch4 = (const float4*)chrow;

  float4 chreg[2];
  chreg[0] = ch4[tid];           // vars 4*tid .. 4*tid+3
  chreg[1] = ch4[1024 + tid];    // vars 4096+4*tid ..

  float w[NITER];
#pragma unroll
  for (int i = 0; i < NITER; ++i) w[i] = wts[i];

  // Preload slot indices (writes) and masked var indices (vl reads).
  int idx[4][6];
  int vidx[4][6];
#pragma unroll
  for (int r = 0; r < 4; ++r) {
    int c = tid + r * 1024;
    unsigned int p0 = slotp[c];
    unsigned int p1 = slotp[NC + c];
    unsigned int p2 = slotp[2 * NC + c];
    idx[r][0] = (int)(p0 & 0xFFFFu); idx[r][1] = (int)(p0 >> 16);
    idx[r][2] = (int)(p1 & 0xFFFFu); idx[r][3] = (int)(p1 >> 16);
    idx[r][4] = (int)(p2 & 0xFFFFu); idx[r][5] = (int)(p2 >> 16);
#pragma unroll
    for (int j = 0; j < 6; ++j) vidx[r][j] = idx[r][j] & (NV - 1);
  }

  // c2v for this thread's 4 checks, resident in registers across iterations.
  float creg[4][6];
#pragma unroll
  for (int r = 0; r < 4; ++r)
#pragma unroll
    for (int j = 0; j < 6; ++j) creg[r][j] = 0.0f;

  float4* m0 = (float4*)&s_msg[0];
  float4* m1 = (float4*)&s_msg[NV];
  float4* m2 = (float4*)&s_msg[2 * NV];
  float4* vl4 = (float4*)s_vl;

  // ---- init: vl = ch (it0 v2c = vl - 0 = ch) ------------------------------
#pragma unroll
  for (int p = 0; p < 2; ++p) vl4[p * 1024 + tid] = chreg[p];
  __syncthreads();

  for (int it = 0; it < NITER; ++it) {
    const float wi = w[it];

    // ---- Phase B: hoist ALL 24 vl reads (independent, pipelined) ----------
    float tv[4][6];
#pragma unroll
    for (int r = 0; r < 4; ++r)
#pragma unroll
      for (int j = 0; j < 6; ++j) tv[r][j] = s_vl[vidx[r][j]];

    // ---- Phase B compute + writes -----------------------------------------
#pragma unroll
    for (int r = 0; r < 4; ++r) {
      unsigned int u[6];
      float av[6];
      unsigned int xs = 0u;
#pragma unroll
      for (int j = 0; j < 6; ++j) {
        float t = tv[r][j] - creg[r][j];
        unsigned int uu = __float_as_uint(t);
        u[j] = uu;
        xs ^= uu;
        av[j] = __uint_as_float(uu & 0x7FFFFFFFu);
      }
      // 2-min tree: exact, order-independent (min3/med3/max)
      float m1a = fminf(fminf(av[0], av[1]), av[2]);
      float m1b = fminf(fminf(av[3], av[4]), av[5]);
      float meda = __builtin_amdgcn_fmed3f(av[0], av[1], av[2]);
      float medb = __builtin_amdgcn_fmed3f(av[3], av[4], av[5]);
      float m1v = fminf(m1a, m1b);
      float m2v = fminf(fminf(meda, medb), fmaxf(m1a, m1b));
      const bool anyz = (m1v == 0.0f);
      const float m1w = m1v * wi;
      const float m2w = m2v * wi;
#pragma unroll
      for (int j = 0; j < 6; ++j) {
        float mag = (av[j] == m1v) ? m2w : m1w;  // ties: m2v==m1v, matches ref
        unsigned int s = (xs ^ u[j]) & 0x80000000u;
        float o = __uint_as_float(__float_as_uint(mag) ^ s);
        if (anyz) o = 0.0f;
        creg[r][j] = o;
        s_msg[idx[r][j]] = o;
      }
    }
    __syncthreads();

    // ---- Phase A: vl = ch + ((c0+c1)+c2), one wide write ------------------
    if (it < NITER - 1) {
#pragma unroll
      for (int p = 0; p < 2; ++p) {
        int i4 = p * 1024 + tid;
        float4 c0 = m0[i4], c1 = m1[i4], c2 = m2[i4];
        float4 cr = chreg[p];
        float4 vl;
        vl.x = cr.x + ((c0.x + c1.x) + c2.x);   // np.add.at association
        vl.y = cr.y + ((c0.y + c1.y) + c2.y);
        vl.z = cr.z + ((c0.z + c1.z) + c2.z);
        vl.w = cr.w + ((c0.w + c1.w) + c2.w);
        vl4[i4] = vl;
      }
      __syncthreads();
    }
  }

  // ---- Final: out = ch + ((c0+c1)+c2), float4 stores ----------------------
  float4* orow4 = (float4*)(out + (size_t)b * NV);
#pragma unroll
  for (int p = 0; p < 2; ++p) {
    int i4 = p * 1024 + tid;
    float4 c0 = m0[i4], c1 = m1[i4], c2 = m2[i4];
    float4 cr = chreg[p];
    float4 o;
    o.x = cr.x + ((c0.x + c1.x) + c2.x);
    o.y = cr.y + ((c0.y + c1.y) + c2.y);
    o.z = cr.z + ((c0.z + c1.z) + c2.z);
    o.w = cr.w + ((c0.w + c1.w) + c2.w);
    orow4[i4] = o;
  }
}

// ---------------------------------------------------------------------------

extern "C" void kernel_launch(void* const* d_in, const int* in_sizes, int n_in,
                              void* d_out, int out_size, void* d_ws, size_t ws_size,
                              hipStream_t stream) {
  (void)in_sizes; (void)n_in; (void)out_size; (void)ws_size;

  const float* ch   = (const float*)d_in[0];   // [BATCH, NV] f32
  const float* wts  = (const float*)d_in[1];   // [NITER, 1] f32
  const int*  Hcols = (const int*)d_in[3];     // [NE] i32
  float* out = (float*)d_out;

  char* ws = (char*)d_ws;
  int*            cnt     = (int*)(ws + 0);                  // 32768 B
  unsigned short* v2e_tmp = (unsigned short*)(ws + 32768);   // 49152 B
  unsigned short* cslot   = (unsigned short*)(ws + 81920);   // 49152 B
  unsigned int*   slotp   = (unsigned int*)(ws + 131072);    // 49152 B
  // total ws use: 180224 B

  hipMemsetAsync(cnt, 0, NV * sizeof(int), stream);
  build_v2e<<<(NE + 255) / 256, 256, 0, stream>>>(Hcols, cnt, v2e_tmp);
  invert_slots<<<(NV + 255) / 256, 256, 0, stream>>>(v2e_tmp, cslot);
  greedy_schedule<<<NC / 64, 64, 0, stream>>>(cslot, slotp);

  decode_kernel<<<BATCH, 1024, 0, stream>>>(ch, wts, slotp, out);
}